// Round 1
// baseline (5185.631 us; speedup 1.0000x reference)
//
#include <hip/hip_runtime.h>
#include <math.h>

#define NB       8
#define SEQ      8192
#define L1OUT    2048
#define LOUT     1024
#define DMODEL   256
#define DINNER   1024
#define NHEADS   16
#define HEADDIM  64
#define DSTATE   64
#define CONVDIM  1152
#define DINPROJ  2192
#define NLAYERS  8

__device__ __forceinline__ float gelu_f(float v) {
    return 0.5f * v * (1.0f + erff(v * 0.70710678118654752f));
}
__device__ __forceinline__ float silu_f(float v) {
    return v / (1.0f + expf(-v));
}

// ---------------- conv1 (3->64, k16, s4, pad6) + GELU ----------------
__global__ __launch_bounds__(256) void k_conv1(const float* __restrict__ x,
                                               const float* __restrict__ w,
                                               const float* __restrict__ bias,
                                               float* __restrict__ out) {
    int idx = blockIdx.x * 256 + threadIdx.x;      // NB*64*L1OUT = 1048576
    int t  = idx & (L1OUT - 1);
    int co = (idx >> 11) & 63;
    int b  = idx >> 17;
    float s = bias[co];
#pragma unroll
    for (int ci = 0; ci < 3; ++ci) {
        const float* xp = x + ((size_t)b * 3 + ci) * SEQ;
        const float* wp = w + (co * 3 + ci) * 16;
#pragma unroll
        for (int k = 0; k < 16; ++k) {
            int pos = t * 4 + k - 6;
            if (pos >= 0 && pos < SEQ) s = fmaf(xp[pos], wp[k], s);
        }
    }
    out[idx] = gelu_f(s);
}

// ---------------- im2col for conv2 (64ch, k16, s2, pad7) ----------------
__global__ __launch_bounds__(256) void k_im2col(const float* __restrict__ h1,
                                                float* __restrict__ A) {
    int idx = blockIdx.x * 256 + threadIdx.x;      // 8192*1024
    int col = idx & 1023;
    int row = idx >> 10;
    int t = row & (LOUT - 1);
    int b = row >> 10;
    int ci = col >> 4, k = col & 15;
    int pos = t * 2 + k - 7;
    float v = 0.f;
    if (pos >= 0 && pos < L1OUT) v = h1[((size_t)b * 64 + ci) * L1OUT + pos];
    A[idx] = v;
}

// ---------------- tiled fp32 GEMM: C[M,N] = A[M,K] * B[N,K]^T ----------------
// 128x128 tile, 256 threads, 8x8 per thread, BK=8. M % 128 == 0, K % 8 == 0.
// epi: 0 = plain store, 1 = gelu(v + bias[col])
__global__ __launch_bounds__(256) void k_gemm(const float* __restrict__ A,
                                              const float* __restrict__ Bw,
                                              float* __restrict__ C,
                                              int M, int N, int K,
                                              const float* __restrict__ bias,
                                              int epi) {
    __shared__ float As[8][128];
    __shared__ float Bs[8][128];
    int tid  = threadIdx.x;
    int row0 = blockIdx.y * 128, col0 = blockIdx.x * 128;
    int tx = tid & 15, ty = tid >> 4;
    int ar = tid >> 1, ac = (tid & 1) << 2;

    float acc[8][8];
#pragma unroll
    for (int i = 0; i < 8; ++i)
#pragma unroll
        for (int j = 0; j < 8; ++j) acc[i][j] = 0.f;

    const float* Aptr = A + (size_t)(row0 + ar) * K + ac;
    int brow = col0 + ar;
    const float* Bptr = Bw + (size_t)brow * K + ac;
    bool bok = brow < N;

    for (int k0 = 0; k0 < K; k0 += 8) {
        float4 a4 = *reinterpret_cast<const float4*>(Aptr + k0);
        float4 b4 = make_float4(0.f, 0.f, 0.f, 0.f);
        if (bok) b4 = *reinterpret_cast<const float4*>(Bptr + k0);
        __syncthreads();
        As[ac + 0][ar] = a4.x; As[ac + 1][ar] = a4.y;
        As[ac + 2][ar] = a4.z; As[ac + 3][ar] = a4.w;
        Bs[ac + 0][ar] = b4.x; Bs[ac + 1][ar] = b4.y;
        Bs[ac + 2][ar] = b4.z; Bs[ac + 3][ar] = b4.w;
        __syncthreads();
#pragma unroll
        for (int kk = 0; kk < 8; ++kk) {
            float av[8], bv[8];
#pragma unroll
            for (int i = 0; i < 8; ++i) av[i] = As[kk][ty * 8 + i];
#pragma unroll
            for (int j = 0; j < 8; ++j) bv[j] = Bs[kk][tx * 8 + j];
#pragma unroll
            for (int i = 0; i < 8; ++i)
#pragma unroll
                for (int j = 0; j < 8; ++j)
                    acc[i][j] = fmaf(av[i], bv[j], acc[i][j]);
        }
    }
#pragma unroll
    for (int i = 0; i < 8; ++i) {
        int r = row0 + ty * 8 + i;
#pragma unroll
        for (int j = 0; j < 8; ++j) {
            int c = col0 + tx * 8 + j;
            if (c < N) {
                float v = acc[i][j];
                if (epi == 1) v = gelu_f(v + bias[c]);
                C[(size_t)r * N + c] = v;
            }
        }
    }
}

// ---------------- depthwise causal conv (k=4) + SiLU on xBC ----------------
__global__ __launch_bounds__(256) void k_dwconv(const float* __restrict__ zx,
                                                const float* __restrict__ w,
                                                const float* __restrict__ bias,
                                                float* __restrict__ out) {
    int idx = blockIdx.x * 256 + threadIdx.x;      // NB*LOUT*CONVDIM
    int c  = idx % CONVDIM;
    int bl = idx / CONVDIM;
    int l  = bl & (LOUT - 1);
    const float* wp = w + c * 4;
    float s = bias[c];
#pragma unroll
    for (int k = 0; k < 4; ++k) {
        int t = l - 3 + k;
        if (t >= 0) s = fmaf(zx[(size_t)(bl - 3 + k) * DINPROJ + DINNER + c], wp[k], s);
    }
    out[idx] = silu_f(s);
}

// ---------------- dt = softplus(raw + bias); dA = exp(-exp(A_log)*dt) -------
__global__ __launch_bounds__(256) void k_dt(const float* __restrict__ zx,
                                            const float* __restrict__ dt_bias,
                                            const float* __restrict__ A_log,
                                            float* __restrict__ dt,
                                            float* __restrict__ dA) {
    int idx = blockIdx.x * 256 + threadIdx.x;      // NB*LOUT*NHEADS
    int hh = idx & 15;
    int bl = idx >> 4;
    float raw = zx[(size_t)bl * DINPROJ + DINNER + CONVDIM + hh] + dt_bias[hh];
    float dtv = (raw > 20.f) ? raw : log1pf(expf(raw));
    dt[idx] = dtv;
    dA[idx] = expf(-expf(A_log[hh]) * dtv);
}

// ---------------- selective scan: one block per (b, head) ----------------
// thread t: p = t>>2 (HEADDIM row), nq = t&3 -> n in [nq*16, nq*16+16)
__global__ __launch_bounds__(256) void k_scan(const float* __restrict__ xbc,
                                              const float* __restrict__ dt,
                                              const float* __restrict__ dA,
                                              float* __restrict__ yout) {
    __shared__ float sbuf[8][192];
    __shared__ float sdA[8], sdt[8];
    int tid = threadIdx.x;
    int b = blockIdx.x >> 4, hh = blockIdx.x & 15;
    int p = tid >> 2, nq = tid & 3;
    const size_t base = (size_t)b * LOUT;
    int ch = (tid < 64) ? (hh * 64 + tid) : (960 + tid);   // x / B / C channel

    float h[16];
#pragma unroll
    for (int i = 0; i < 16; ++i) h[i] = 0.f;

    float pre[8];
    if (tid < 192) {
#pragma unroll
        for (int s = 0; s < 8; ++s) pre[s] = xbc[(base + s) * CONVDIM + ch];
    } else if (tid < 200) {
        pre[0] = dA[(base + (tid - 192)) * NHEADS + hh];
    } else if (tid < 208) {
        pre[0] = dt[(base + (tid - 200)) * NHEADS + hh];
    }

    for (int c0 = 0; c0 < LOUT / 8; ++c0) {
        __syncthreads();
        if (tid < 192) {
#pragma unroll
            for (int s = 0; s < 8; ++s) sbuf[s][tid] = pre[s];
        } else if (tid < 200) sdA[tid - 192] = pre[0];
        else if (tid < 208)   sdt[tid - 200] = pre[0];
        __syncthreads();

        int lnext = (c0 + 1) * 8;
        if (lnext < LOUT) {
            if (tid < 192) {
#pragma unroll
                for (int s = 0; s < 8; ++s) pre[s] = xbc[(base + lnext + s) * CONVDIM + ch];
            } else if (tid < 200) pre[0] = dA[(base + lnext + (tid - 192)) * NHEADS + hh];
            else if (tid < 208)   pre[0] = dt[(base + lnext + (tid - 200)) * NHEADS + hh];
        }

#pragma unroll
        for (int s = 0; s < 8; ++s) {
            float dAv = sdA[s], dtv = sdt[s];
            float cc = dtv * sbuf[s][p];
            float ysum = 0.f;
            const float* Bp = &sbuf[s][64 + nq * 16];
            const float* Cp = &sbuf[s][128 + nq * 16];
#pragma unroll
            for (int i = 0; i < 16; ++i) {
                h[i] = fmaf(h[i], dAv, cc * Bp[i]);
                ysum = fmaf(h[i], Cp[i], ysum);
            }
            ysum += __shfl_xor(ysum, 1);
            ysum += __shfl_xor(ysum, 2);
            if (nq == 0)
                yout[(base + c0 * 8 + s) * DINNER + hh * 64 + p] = ysum;
        }
    }
}

// ---------------- y = (yss + D*xh) * silu(z); RMSNorm * rms_w (in place) ----
__global__ __launch_bounds__(256) void k_gate(const float* __restrict__ zx,
                                              const float* __restrict__ xbc,
                                              const float* __restrict__ ssmD,
                                              const float* __restrict__ rmsw,
                                              float* __restrict__ y) {
    __shared__ float sh[4];
    int bl = blockIdx.x, tid = threadIdx.x;
    int c = tid * 4;
    float4 ys = *reinterpret_cast<const float4*>(&y[(size_t)bl * DINNER + c]);
    float4 xh = *reinterpret_cast<const float4*>(&xbc[(size_t)bl * CONVDIM + c]);
    float4 z4 = *reinterpret_cast<const float4*>(&zx[(size_t)bl * DINPROJ + c]);
    float Dv = ssmD[tid >> 4];
    float v[4] = {ys.x, ys.y, ys.z, ys.w};
    float xv[4] = {xh.x, xh.y, xh.z, xh.w};
    float zv[4] = {z4.x, z4.y, z4.z, z4.w};
    float ss = 0.f;
#pragma unroll
    for (int j = 0; j < 4; ++j) {
        v[j] = (v[j] + Dv * xv[j]) * silu_f(zv[j]);
        ss += v[j] * v[j];
    }
    int lane = tid & 63, wid = tid >> 6;
#pragma unroll
    for (int o = 32; o > 0; o >>= 1) ss += __shfl_down(ss, o, 64);
    if (lane == 0) sh[wid] = ss;
    __syncthreads();
    float total = sh[0] + sh[1] + sh[2] + sh[3];
    float r = rsqrtf(total * (1.f / DINNER) + 1e-5f);
    float4 o4;
    o4.x = v[0] * r * rmsw[c + 0];
    o4.y = v[1] * r * rmsw[c + 1];
    o4.z = v[2] * r * rmsw[c + 2];
    o4.w = v[3] * r * rmsw[c + 3];
    *reinterpret_cast<float4*>(&y[(size_t)bl * DINNER + c]) = o4;
}

// ---------------- final LayerNorm + mean pool (atomics) ----------------
__global__ __launch_bounds__(256) void k_lnpool(const float* __restrict__ h,
                                                const float* __restrict__ lnw,
                                                const float* __restrict__ lnb,
                                                float* __restrict__ pooled) {
    __shared__ float sh1[4], sh2[4];
    int bl = blockIdx.x, c = threadIdx.x;
    float v = h[(size_t)bl * DMODEL + c];
    float s1 = v, s2 = v * v;
    int lane = c & 63, wid = c >> 6;
#pragma unroll
    for (int o = 32; o > 0; o >>= 1) {
        s1 += __shfl_down(s1, o, 64);
        s2 += __shfl_down(s2, o, 64);
    }
    if (lane == 0) { sh1[wid] = s1; sh2[wid] = s2; }
    __syncthreads();
    float t1 = sh1[0] + sh1[1] + sh1[2] + sh1[3];
    float t2 = sh2[0] + sh2[1] + sh2[2] + sh2[3];
    float mu = t1 * (1.f / DMODEL);
    float var = t2 * (1.f / DMODEL) - mu * mu;
    float o = (v - mu) * rsqrtf(var + 1e-5f) * lnw[c] + lnb[c];
    atomicAdd(&pooled[(bl >> 10) * DMODEL + c], o * (1.f / LOUT));
}

__global__ void k_zero(float* __restrict__ p, int n) {
    int i = blockIdx.x * 256 + threadIdx.x;
    if (i < n) p[i] = 0.f;
}

// ---------------- regression head ----------------
__global__ __launch_bounds__(128) void k_head(const float* __restrict__ pooled,
                                              const float* __restrict__ w1,
                                              const float* __restrict__ b1,
                                              const float* __restrict__ w2,
                                              const float* __restrict__ b2,
                                              float* __restrict__ out) {
    __shared__ float red[2];
    int b = blockIdx.x, j = threadIdx.x;
    float acc = b1[j];
#pragma unroll 8
    for (int d = 0; d < DMODEL; ++d)
        acc = fmaf(pooled[b * DMODEL + d], w1[j * DMODEL + d], acc);
    float r = gelu_f(acc) * w2[j];
#pragma unroll
    for (int o = 32; o > 0; o >>= 1) r += __shfl_down(r, o, 64);
    int lane = j & 63, wid = j >> 6;
    if (lane == 0) red[wid] = r;
    __syncthreads();
    if (j == 0) out[b] = red[0] + red[1] + b2[0];
}

extern "C" void kernel_launch(void* const* d_in, const int* in_sizes, int n_in,
                              void* d_out, int out_size, void* d_ws, size_t ws_size,
                              hipStream_t stream) {
    const float* x         = (const float*)d_in[0];
    const float* conv1_w   = (const float*)d_in[1];
    const float* conv1_b   = (const float*)d_in[2];
    const float* conv2_w   = (const float*)d_in[3];
    const float* conv2_b   = (const float*)d_in[4];
    const float* in_proj_w = (const float*)d_in[5];
    const float* dw_w      = (const float*)d_in[6];
    const float* dw_b      = (const float*)d_in[7];
    const float* dt_bias   = (const float*)d_in[8];
    const float* A_log     = (const float*)d_in[9];
    const float* ssm_D     = (const float*)d_in[10];
    const float* rms_w     = (const float*)d_in[11];
    const float* out_proj_w= (const float*)d_in[12];
    const float* ln_w      = (const float*)d_in[13];
    const float* ln_b      = (const float*)d_in[14];
    const float* reg1_w    = (const float*)d_in[15];
    const float* reg1_b    = (const float*)d_in[16];
    const float* reg2_w    = (const float*)d_in[17];
    const float* reg2_b    = (const float*)d_in[18];

    float* ws = (float*)d_ws;
    size_t off = 0;
    float* c1buf  = ws + off; off += (size_t)NB * 64 * L1OUT;       // 1,048,576
    float* hbuf0  = ws + off; off += (size_t)NB * LOUT * DMODEL;    // 2,097,152
    float* hbuf1  = ws + off; off += (size_t)NB * LOUT * DMODEL;    // 2,097,152
    float* zx     = ws + off; off += (size_t)NB * LOUT * DINPROJ;   // 17,956,864
    float* xbcc   = ws + off; off += (size_t)NB * LOUT * CONVDIM;   // 9,437,184
    float* dtb    = ws + off; off += (size_t)NB * LOUT * NHEADS;    // 131,072
    float* dab    = ws + off; off += (size_t)NB * LOUT * NHEADS;    // 131,072
    float* yss    = ws + off; off += (size_t)NB * LOUT * DINNER;    // 8,388,608
    float* pooled = ws + off; off += NB * DMODEL;                   // 2,048
    float* im2col = yss;   // aliased: im2col used only before the layer loop

    // front-end convs
    k_conv1<<<(NB * 64 * L1OUT) / 256, 256, 0, stream>>>(x, conv1_w, conv1_b, c1buf);
    k_im2col<<<(NB * LOUT * 1024) / 256, 256, 0, stream>>>(c1buf, im2col);
    {
        dim3 g(256 / 128, 8192 / 128);  // N=256, M=8192
        k_gemm<<<g, 256, 0, stream>>>(im2col, conv2_w, hbuf0, 8192, 256, 1024, conv2_b, 1);
    }

    float* hcur = hbuf0;
    float* hnxt = hbuf1;
    for (int i = 0; i < NLAYERS; ++i) {
        {
            dim3 g((DINPROJ + 127) / 128, 8192 / 128);  // 18 x 64
            k_gemm<<<g, 256, 0, stream>>>(hcur, in_proj_w + (size_t)i * DINPROJ * DMODEL,
                                          zx, 8192, DINPROJ, DMODEL, nullptr, 0);
        }
        k_dwconv<<<(NB * LOUT * CONVDIM) / 256, 256, 0, stream>>>(
            zx, dw_w + (size_t)i * CONVDIM * 4, dw_b + (size_t)i * CONVDIM, xbcc);
        k_dt<<<(NB * LOUT * NHEADS) / 256, 256, 0, stream>>>(
            zx, dt_bias + i * NHEADS, A_log + i * NHEADS, dtb, dab);
        k_scan<<<NB * NHEADS, 256, 0, stream>>>(xbcc, dtb, dab, yss);
        k_gate<<<NB * LOUT, 256, 0, stream>>>(zx, xbcc, ssm_D + i * NHEADS,
                                              rms_w + (size_t)i * DINNER, yss);
        {
            dim3 g(DMODEL / 128, 8192 / 128);  // 2 x 64
            k_gemm<<<g, 256, 0, stream>>>(yss, out_proj_w + (size_t)i * DMODEL * DINNER,
                                          hnxt, 8192, DMODEL, DINNER, nullptr, 0);
        }
        float* tmp = hcur; hcur = hnxt; hnxt = tmp;
    }

    // final LN + pool + head
    k_zero<<<(NB * DMODEL + 255) / 256, 256, 0, stream>>>(pooled, NB * DMODEL);
    k_lnpool<<<NB * LOUT, 256, 0, stream>>>(hcur, ln_w, ln_b, pooled);
    k_head<<<NB, 128, 0, stream>>>(pooled, reg1_w, reg1_b, reg2_w, reg2_b, (float*)d_out);
}

// Round 2
// 3151.017 us; speedup vs baseline: 1.6457x; 1.6457x over previous
//
#include <hip/hip_runtime.h>
#include <math.h>

#define NB       8
#define SEQ      8192
#define L1OUT    2048
#define LOUT     1024
#define DMODEL   256
#define DINNER   1024
#define NHEADS   16
#define HEADDIM  64
#define DSTATE   64
#define CONVDIM  1152
#define DINPROJ  2192
#define NPADIN   2304     // in_proj rows padded to multiple of 128
#define NLAYERS  8

typedef _Float16 f16;
typedef __attribute__((ext_vector_type(8))) _Float16 f16x8;
typedef __attribute__((ext_vector_type(4))) _Float16 f16x4;
typedef __attribute__((ext_vector_type(4))) float    f32x4;

__device__ __forceinline__ float gelu_f(float v) {
    return 0.5f * v * (1.0f + erff(v * 0.70710678118654752f));
}
__device__ __forceinline__ float silu_f(float v) {
    return v / (1.0f + expf(-v));
}

__device__ __forceinline__ void gload16(const void* g, void* l) {
    __builtin_amdgcn_global_load_lds(
        (const __attribute__((address_space(1))) unsigned int*)g,
        (__attribute__((address_space(3))) unsigned int*)l, 16, 0, 0);
}

// ---------------- weight casts ----------------
__global__ __launch_bounds__(256) void k_cast(const float* __restrict__ in,
                                              f16* __restrict__ out, int n) {
    int i = blockIdx.x * 256 + threadIdx.x;
    if (i < n) out[i] = (f16)in[i];
}

// in_proj: [8][2192][256] fp32 -> [8][2304][256] f16, zero-padded rows
__global__ __launch_bounds__(256) void k_cast_inproj(const float* __restrict__ w,
                                                     f16* __restrict__ out) {
    int idx = blockIdx.x * 256 + threadIdx.x;       // 8*2304*256
    int c = idx & 255;
    int r = (idx >> 8) % NPADIN;
    int l = idx / (NPADIN * 256);
    float v = (r < DINPROJ) ? w[((size_t)l * DINPROJ + r) * 256 + c] : 0.f;
    out[idx] = (f16)v;
}

// ---------------- conv1 (3->64, k16, s4, pad6) + GELU ----------------
__global__ __launch_bounds__(256) void k_conv1(const float* __restrict__ x,
                                               const float* __restrict__ w,
                                               const float* __restrict__ bias,
                                               float* __restrict__ out) {
    int idx = blockIdx.x * 256 + threadIdx.x;      // NB*64*L1OUT
    int t  = idx & (L1OUT - 1);
    int co = (idx >> 11) & 63;
    int b  = idx >> 17;
    float s = bias[co];
#pragma unroll
    for (int ci = 0; ci < 3; ++ci) {
        const float* xp = x + ((size_t)b * 3 + ci) * SEQ;
        const float* wp = w + (co * 3 + ci) * 16;
#pragma unroll
        for (int k = 0; k < 16; ++k) {
            int pos = t * 4 + k - 6;
            if (pos >= 0 && pos < SEQ) s = fmaf(xp[pos], wp[k], s);
        }
    }
    out[idx] = gelu_f(s);
}

// ---------------- im2col for conv2 (64ch, k16, s2, pad7) -> f16 ----------------
__global__ __launch_bounds__(256) void k_im2col(const float* __restrict__ h1,
                                                f16* __restrict__ A) {
    int idx = blockIdx.x * 256 + threadIdx.x;      // 8192*1024
    int col = idx & 1023;
    int row = idx >> 10;
    int t = row & (LOUT - 1);
    int b = row >> 10;
    int ci = col >> 4, k = col & 15;
    int pos = t * 2 + k - 7;
    float v = 0.f;
    if (pos >= 0 && pos < L1OUT) v = h1[((size_t)b * 64 + ci) * L1OUT + pos];
    A[idx] = (f16)v;
}

// ---------------- fp16 MFMA GEMM: C[M,N] = A[M,K] * B[Npad,K]^T ----------------
// BM x 128 tile, 256 threads (4 waves in 2x2), BK=32, 16x16x32 f16 MFMA.
// EPI: 0 plain, 1 gelu(v + bias[col]). Cf (fp32) and Ch (f16) both optional.
template<int BM, int EPI>
__global__ __launch_bounds__(256) void k_hgemm(const f16* __restrict__ A,
                                               const f16* __restrict__ Bw,
                                               float* __restrict__ Cf,
                                               f16* __restrict__ Ch,
                                               int M, int N, int K,
                                               const float* __restrict__ bias) {
    constexpr int MI = BM / 32;
    __shared__ f16 As[BM * 32];
    __shared__ f16 Bs[128 * 32];
    int tid  = threadIdx.x;
    int lane = tid & 63, wid = tid >> 6;
    int wm = wid >> 1, wn = wid & 1;
    int row0 = blockIdx.y * BM, col0 = blockIdx.x * 128;
    int lr = lane & 15, kb = lane >> 4;

    f32x4 acc[MI][4];
#pragma unroll
    for (int mi = 0; mi < MI; ++mi)
#pragma unroll
        for (int ni = 0; ni < 4; ++ni)
            acc[mi][ni] = (f32x4){0.f, 0.f, 0.f, 0.f};

    int srow = tid >> 2;             // staging row within 64-row slab
    int scol = (tid & 3) * 8;        // staging k-offset (8 f16 = 16 B)

    for (int k0 = 0; k0 < K; k0 += 32) {
        __syncthreads();
#pragma unroll
        for (int is = 0; is < BM / 64; ++is)
            gload16(A + (size_t)(row0 + is * 64 + srow) * K + k0 + scol,
                    &As[is * 2048 + wid * 512]);
#pragma unroll
        for (int is = 0; is < 2; ++is)
            gload16(Bw + (size_t)(col0 + is * 64 + srow) * K + k0 + scol,
                    &Bs[is * 2048 + wid * 512]);
        __syncthreads();

        f16x8 a[MI], b[4];
#pragma unroll
        for (int mi = 0; mi < MI; ++mi)
            a[mi] = *reinterpret_cast<const f16x8*>(
                &As[(wm * (BM / 2) + mi * 16 + lr) * 32 + kb * 8]);
#pragma unroll
        for (int ni = 0; ni < 4; ++ni)
            b[ni] = *reinterpret_cast<const f16x8*>(
                &Bs[(wn * 64 + ni * 16 + lr) * 32 + kb * 8]);
#pragma unroll
        for (int mi = 0; mi < MI; ++mi)
#pragma unroll
            for (int ni = 0; ni < 4; ++ni)
                acc[mi][ni] = __builtin_amdgcn_mfma_f32_16x16x32_f16(
                    a[mi], b[ni], acc[mi][ni], 0, 0, 0);
    }

#pragma unroll
    for (int mi = 0; mi < MI; ++mi)
#pragma unroll
        for (int ni = 0; ni < 4; ++ni) {
            int ccol = col0 + wn * 64 + ni * 16 + lr;
            if (ccol < N) {
                int rbase = row0 + wm * (BM / 2) + mi * 16 + kb * 4;
                f32x4 v = acc[mi][ni];
#pragma unroll
                for (int r = 0; r < 4; ++r) {
                    float val = v[r];
                    if (EPI == 1) val = gelu_f(val + bias[ccol]);
                    if (Cf) Cf[(size_t)(rbase + r) * N + ccol] = val;
                    if (Ch) Ch[(size_t)(rbase + r) * N + ccol] = (f16)val;
                }
            }
        }
}

// ---------------- depthwise causal conv (k=4) + SiLU on xBC ----------------
__global__ __launch_bounds__(256) void k_dwconv(const float* __restrict__ zx,
                                                const float* __restrict__ w,
                                                const float* __restrict__ bias,
                                                float* __restrict__ out) {
    int idx = blockIdx.x * 256 + threadIdx.x;      // NB*LOUT*CONVDIM
    int c  = idx % CONVDIM;
    int bl = idx / CONVDIM;
    int l  = bl & (LOUT - 1);
    const float* wp = w + c * 4;
    float s = bias[c];
#pragma unroll
    for (int k = 0; k < 4; ++k) {
        int t = l - 3 + k;
        if (t >= 0) s = fmaf(zx[(size_t)(bl - 3 + k) * DINPROJ + DINNER + c], wp[k], s);
    }
    out[idx] = silu_f(s);
}

// ---------------- dt = softplus(raw + bias); dA = exp(-exp(A_log)*dt) -------
__global__ __launch_bounds__(256) void k_dt(const float* __restrict__ zx,
                                            const float* __restrict__ dt_bias,
                                            const float* __restrict__ A_log,
                                            float* __restrict__ dt,
                                            float* __restrict__ dA) {
    int idx = blockIdx.x * 256 + threadIdx.x;      // NB*LOUT*NHEADS
    int hh = idx & 15;
    int bl = idx >> 4;
    float raw = zx[(size_t)bl * DINPROJ + DINNER + CONVDIM + hh] + dt_bias[hh];
    float dtv = (raw > 20.f) ? raw : log1pf(expf(raw));
    dt[idx] = dtv;
    dA[idx] = expf(-expf(A_log[hh]) * dtv);
}

// ---------------- selective scan ----------------
// grid: NB*NHEADS*4 blocks (one wave each); block owns 16 of the 64 p-rows.
// thread t: pg = t>>3 (2 p's: pq*16+pg*2+{0,1}), ng = t&7 (8 n's: ng*8..+8)
__global__ __launch_bounds__(64) void k_scan(const float* __restrict__ xbc,
                                             const float* __restrict__ dt,
                                             const float* __restrict__ dA,
                                             float* __restrict__ yout) {
    __shared__ float sx[8][16];
    __shared__ float sB[8][64];
    __shared__ float sC[8][64];
    __shared__ float sdA[8], sdt[8];
    int tid = threadIdx.x;
    int bid = blockIdx.x;
    int pq = bid & 3, hh = (bid >> 2) & 15, b = bid >> 6;
    int pg = tid >> 3, ng = tid & 7;
    size_t base = (size_t)b * LOUT;
    int sS = tid >> 3, sc = tid & 7;     // staging role: step sS, slot sc

    float h0[8], h1[8];
#pragma unroll
    for (int j = 0; j < 8; ++j) { h0[j] = 0.f; h1[j] = 0.f; }

    float4 pB0, pB1, pC0, pC1;
    float2 px;
    float pda, pdtv;

#define LOADPRE(L0)                                                        \
    {                                                                      \
        size_t rr = (base + (L0) + sS) * CONVDIM;                          \
        pB0 = *(const float4*)&xbc[rr + DINNER + sc * 8];                  \
        pB1 = *(const float4*)&xbc[rr + DINNER + sc * 8 + 4];              \
        pC0 = *(const float4*)&xbc[rr + DINNER + DSTATE + sc * 8];         \
        pC1 = *(const float4*)&xbc[rr + DINNER + DSTATE + sc * 8 + 4];     \
        px  = *(const float2*)&xbc[rr + hh * 64 + pq * 16 + sc * 2];       \
        pda = dA[(base + (L0) + sS) * NHEADS + hh];                        \
        pdtv = dt[(base + (L0) + sS) * NHEADS + hh];                       \
    }

    LOADPRE(0);
    for (int c0 = 0; c0 < LOUT / 8; ++c0) {
        *(float4*)&sB[sS][sc * 8]     = pB0;
        *(float4*)&sB[sS][sc * 8 + 4] = pB1;
        *(float4*)&sC[sS][sc * 8]     = pC0;
        *(float4*)&sC[sS][sc * 8 + 4] = pC1;
        *(float2*)&sx[sS][sc * 2]     = px;
        if (sc == 0) { sdA[sS] = pda; sdt[sS] = pdtv; }
        __syncthreads();
        if (c0 + 1 < LOUT / 8) LOADPRE((c0 + 1) * 8);

#pragma unroll
        for (int s = 0; s < 8; ++s) {
            float dAv = sdA[s], dtv = sdt[s];
            float2 xv = *(const float2*)&sx[s][pg * 2];
            float4 b0 = *(const float4*)&sB[s][ng * 8];
            float4 b1 = *(const float4*)&sB[s][ng * 8 + 4];
            float4 c0v = *(const float4*)&sC[s][ng * 8];
            float4 c1v = *(const float4*)&sC[s][ng * 8 + 4];
            float bb[8] = {b0.x, b0.y, b0.z, b0.w, b1.x, b1.y, b1.z, b1.w};
            float cv[8] = {c0v.x, c0v.y, c0v.z, c0v.w, c1v.x, c1v.y, c1v.z, c1v.w};
            float cc0 = dtv * xv.x, cc1 = dtv * xv.y;
            float ys0 = 0.f, ys1 = 0.f;
#pragma unroll
            for (int j = 0; j < 8; ++j) {
                h0[j] = fmaf(h0[j], dAv, cc0 * bb[j]);
                ys0 = fmaf(h0[j], cv[j], ys0);
                h1[j] = fmaf(h1[j], dAv, cc1 * bb[j]);
                ys1 = fmaf(h1[j], cv[j], ys1);
            }
            ys0 += __shfl_xor(ys0, 1); ys1 += __shfl_xor(ys1, 1);
            ys0 += __shfl_xor(ys0, 2); ys1 += __shfl_xor(ys1, 2);
            ys0 += __shfl_xor(ys0, 4); ys1 += __shfl_xor(ys1, 4);
            if (ng == 0) {
                float2 o = make_float2(ys0, ys1);
                *(float2*)&yout[(base + c0 * 8 + s) * DINNER + hh * 64 + pq * 16 + pg * 2] = o;
            }
        }
        __syncthreads();
    }
#undef LOADPRE
}

// ------ y = (yss + D*xh) * silu(z); RMSNorm * rms_w; write f16 for out_proj ----
__global__ __launch_bounds__(256) void k_gate(const float* __restrict__ zx,
                                              const float* __restrict__ xbc,
                                              const float* __restrict__ ssmD,
                                              const float* __restrict__ rmsw,
                                              const float* __restrict__ y,
                                              f16* __restrict__ ygate) {
    __shared__ float sh[4];
    int bl = blockIdx.x, tid = threadIdx.x;
    int c = tid * 4;
    float4 ys = *reinterpret_cast<const float4*>(&y[(size_t)bl * DINNER + c]);
    float4 xh = *reinterpret_cast<const float4*>(&xbc[(size_t)bl * CONVDIM + c]);
    float4 z4 = *reinterpret_cast<const float4*>(&zx[(size_t)bl * DINPROJ + c]);
    float Dv = ssmD[tid >> 4];
    float v[4] = {ys.x, ys.y, ys.z, ys.w};
    float xv[4] = {xh.x, xh.y, xh.z, xh.w};
    float zv[4] = {z4.x, z4.y, z4.z, z4.w};
    float ss = 0.f;
#pragma unroll
    for (int j = 0; j < 4; ++j) {
        v[j] = (v[j] + Dv * xv[j]) * silu_f(zv[j]);
        ss += v[j] * v[j];
    }
    int lane = tid & 63, wid = tid >> 6;
#pragma unroll
    for (int o = 32; o > 0; o >>= 1) ss += __shfl_down(ss, o, 64);
    if (lane == 0) sh[wid] = ss;
    __syncthreads();
    float total = sh[0] + sh[1] + sh[2] + sh[3];
    float r = rsqrtf(total * (1.f / DINNER) + 1e-5f);
    f16x4 o4;
    o4.x = (f16)(v[0] * r * rmsw[c + 0]);
    o4.y = (f16)(v[1] * r * rmsw[c + 1]);
    o4.z = (f16)(v[2] * r * rmsw[c + 2]);
    o4.w = (f16)(v[3] * r * rmsw[c + 3]);
    *reinterpret_cast<f16x4*>(&ygate[(size_t)bl * DINNER + c]) = o4;
}

// ---------------- final LayerNorm + mean pool (atomics) ----------------
__global__ __launch_bounds__(256) void k_lnpool(const float* __restrict__ h,
                                                const float* __restrict__ lnw,
                                                const float* __restrict__ lnb,
                                                float* __restrict__ pooled) {
    __shared__ float sh1[4], sh2[4];
    int bl = blockIdx.x, c = threadIdx.x;
    float v = h[(size_t)bl * DMODEL + c];
    float s1 = v, s2 = v * v;
    int lane = c & 63, wid = c >> 6;
#pragma unroll
    for (int o = 32; o > 0; o >>= 1) {
        s1 += __shfl_down(s1, o, 64);
        s2 += __shfl_down(s2, o, 64);
    }
    if (lane == 0) { sh1[wid] = s1; sh2[wid] = s2; }
    __syncthreads();
    float t1 = sh1[0] + sh1[1] + sh1[2] + sh1[3];
    float t2 = sh2[0] + sh2[1] + sh2[2] + sh2[3];
    float mu = t1 * (1.f / DMODEL);
    float var = t2 * (1.f / DMODEL) - mu * mu;
    float o = (v - mu) * rsqrtf(var + 1e-5f) * lnw[c] + lnb[c];
    atomicAdd(&pooled[(bl >> 10) * DMODEL + c], o * (1.f / LOUT));
}

__global__ void k_zero(float* __restrict__ p, int n) {
    int i = blockIdx.x * 256 + threadIdx.x;
    if (i < n) p[i] = 0.f;
}

// ---------------- regression head ----------------
__global__ __launch_bounds__(128) void k_head(const float* __restrict__ pooled,
                                              const float* __restrict__ w1,
                                              const float* __restrict__ b1,
                                              const float* __restrict__ w2,
                                              const float* __restrict__ b2,
                                              float* __restrict__ out) {
    __shared__ float red[2];
    int b = blockIdx.x, j = threadIdx.x;
    float acc = b1[j];
#pragma unroll 8
    for (int d = 0; d < DMODEL; ++d)
        acc = fmaf(pooled[b * DMODEL + d], w1[j * DMODEL + d], acc);
    float r = gelu_f(acc) * w2[j];
#pragma unroll
    for (int o = 32; o > 0; o >>= 1) r += __shfl_down(r, o, 64);
    int lane = j & 63, wid = j >> 6;
    if (lane == 0) red[wid] = r;
    __syncthreads();
    if (j == 0) out[b] = red[0] + red[1] + b2[0];
}

extern "C" void kernel_launch(void* const* d_in, const int* in_sizes, int n_in,
                              void* d_out, int out_size, void* d_ws, size_t ws_size,
                              hipStream_t stream) {
    const float* x         = (const float*)d_in[0];
    const float* conv1_w   = (const float*)d_in[1];
    const float* conv1_b   = (const float*)d_in[2];
    const float* conv2_w   = (const float*)d_in[3];
    const float* conv2_b   = (const float*)d_in[4];
    const float* in_proj_w = (const float*)d_in[5];
    const float* dw_w      = (const float*)d_in[6];
    const float* dw_b      = (const float*)d_in[7];
    const float* dt_bias   = (const float*)d_in[8];
    const float* A_log     = (const float*)d_in[9];
    const float* ssm_D     = (const float*)d_in[10];
    const float* rms_w     = (const float*)d_in[11];
    const float* out_proj_w= (const float*)d_in[12];
    const float* ln_w      = (const float*)d_in[13];
    const float* ln_b      = (const float*)d_in[14];
    const float* reg1_w    = (const float*)d_in[15];
    const float* reg1_b    = (const float*)d_in[16];
    const float* reg2_w    = (const float*)d_in[17];
    const float* reg2_b    = (const float*)d_in[18];

    float* ws = (float*)d_ws;
    size_t off = 0;
    float* c1buf  = ws + off; off += (size_t)NB * 64 * L1OUT;       // 1,048,576
    float* hbuf   = ws + off; off += (size_t)NB * LOUT * DMODEL;    // 2,097,152
    float* zx     = ws + off; off += (size_t)NB * LOUT * DINPROJ;   // 17,956,864
    float* xbcc   = ws + off; off += (size_t)NB * LOUT * CONVDIM;   // 9,437,184
    float* dtb    = ws + off; off += (size_t)NB * LOUT * NHEADS;    // 131,072
    float* dab    = ws + off; off += (size_t)NB * LOUT * NHEADS;    // 131,072
    float* yss    = ws + off; off += (size_t)NB * LOUT * DINNER;    // 8,388,608
    float* pooled = ws + off; off += NB * DMODEL;                   // 2,048

    f16* fbase = (f16*)(ws + off);
    size_t foff = 0;
    f16* hbf0   = fbase + foff; foff += (size_t)NB * LOUT * DMODEL;   // 2,097,152
    f16* hbf1   = fbase + foff; foff += (size_t)NB * LOUT * DMODEL;   // 2,097,152
    f16* ygate  = fbase + foff; foff += (size_t)NB * LOUT * DINNER;   // 8,388,608
    f16* w_in_h = fbase + foff; foff += (size_t)NLAYERS * NPADIN * DMODEL;  // 4,718,592
    f16* w_out_h= fbase + foff; foff += (size_t)NLAYERS * DMODEL * DINNER;  // 2,097,152
    f16* w_c2_h = fbase + foff; foff += (size_t)DMODEL * 1024;              // 262,144
    f16* im2h   = (f16*)yss;   // aliased: im2col dead before yss is first written

    // weight casts (every launch; deterministic, ~trivial cost)
    k_cast_inproj<<<(NLAYERS * NPADIN * 256) / 256, 256, 0, stream>>>(in_proj_w, w_in_h);
    k_cast<<<(NLAYERS * DMODEL * DINNER) / 256, 256, 0, stream>>>(
        out_proj_w, w_out_h, NLAYERS * DMODEL * DINNER);
    k_cast<<<(DMODEL * 1024) / 256, 256, 0, stream>>>(conv2_w, w_c2_h, DMODEL * 1024);

    // front-end convs
    k_conv1<<<(NB * 64 * L1OUT) / 256, 256, 0, stream>>>(x, conv1_w, conv1_b, c1buf);
    k_im2col<<<(NB * LOUT * 1024) / 256, 256, 0, stream>>>(c1buf, im2h);
    {
        dim3 g(256 / 128, 8192 / 64);
        k_hgemm<64, 1><<<g, 256, 0, stream>>>(im2h, w_c2_h, nullptr, hbf0,
                                              8192, 256, 1024, conv2_b);
    }

    f16* hcur = hbf0;
    f16* hnxt = hbf1;
    for (int i = 0; i < NLAYERS; ++i) {
        {
            dim3 g(NPADIN / 128, 8192 / 128);
            k_hgemm<128, 0><<<g, 256, 0, stream>>>(
                hcur, w_in_h + (size_t)i * NPADIN * DMODEL, zx, nullptr,
                8192, DINPROJ, DMODEL, nullptr);
        }
        k_dwconv<<<(NB * LOUT * CONVDIM) / 256, 256, 0, stream>>>(
            zx, dw_w + (size_t)i * CONVDIM * 4, dw_b + (size_t)i * CONVDIM, xbcc);
        k_dt<<<(NB * LOUT * NHEADS) / 256, 256, 0, stream>>>(
            zx, dt_bias + i * NHEADS, A_log + i * NHEADS, dtb, dab);
        k_scan<<<NB * NHEADS * 4, 64, 0, stream>>>(xbcc, dtb, dab, yss);
        k_gate<<<NB * LOUT, 256, 0, stream>>>(zx, xbcc, ssm_D + i * NHEADS,
                                              rms_w + (size_t)i * DINNER, yss, ygate);
        {
            dim3 g(DMODEL / 128, 8192 / 64);
            k_hgemm<64, 0><<<g, 256, 0, stream>>>(
                ygate, w_out_h + (size_t)i * DMODEL * DINNER, hbuf, hnxt,
                8192, DMODEL, DINNER, nullptr);
        }
        f16* tmp = hcur; hcur = hnxt; hnxt = tmp;
    }

    // final LN + pool + head
    k_zero<<<(NB * DMODEL + 255) / 256, 256, 0, stream>>>(pooled, NB * DMODEL);
    k_lnpool<<<NB * LOUT, 256, 0, stream>>>(hbuf, ln_w, ln_b, pooled);
    k_head<<<NB, 128, 0, stream>>>(pooled, reg1_w, reg1_b, reg2_w, reg2_b, (float*)d_out);
}